// Round 1
// baseline (892.982 us; speedup 1.0000x reference)
//
#include <hip/hip_runtime.h>
#include <hip/hip_bf16.h>
#include <stdint.h>

#define N_PTS   262144
#define H_DIM   512
#define W_DIM   512
#define N_SEG   16
#define EPS_V   1e-5f

typedef __bf16 bf16_t;
typedef __bf16 bf16x8 __attribute__((ext_vector_type(8)));
typedef float  f32x4  __attribute__((ext_vector_type(4)));

// ---------------- workspace layout (bytes) ----------------
// idx_map   : int[4*512*512]           @ 0          (4194304 B)
// feats_bf  : bf16[N*64]               @ 4194304    (33554432 B)
// h_bf      : bf16[N*64]               @ 37748736   (33554432 B)
// wfrag     : bf16[7*9*2*4*64*8]       @ 71303168   (516096 B)
// stats     : float/int block          @ 71819264   (~50 KB)
//   cnt[16] @0, ymin[16]@16, ymax[16]@32, xmin[16]@48, xmax[16]@64,
//   dseg[3*16]@80, sums[3*1024]@128, sumsq[3*1024]@3200,
//   pA[3*1024]@6272, pB[3*1024]@9344

__global__ void init_kernel(int* cnt, int* ymin, int* ymax, int* xmin, int* xmax,
                            float* sums, float* sumsq) {
  int t = threadIdx.x;
  if (t < N_SEG) {
    cnt[t] = 0;
    ymin[t] = 0x7fffffff; ymax[t] = (int)0x80000000;
    xmin[t] = 0x7fffffff; xmax[t] = (int)0x80000000;
  }
  for (int i = t; i < 3 * 1024; i += 256) { sums[i] = 0.f; sumsq[i] = 0.f; }
}

__global__ void scatter_kernel(const int* __restrict__ indices,
                               const int* __restrict__ seg,
                               int* __restrict__ idx_map,
                               int* __restrict__ cnt,
                               int* __restrict__ ymin, int* __restrict__ ymax,
                               int* __restrict__ xmin, int* __restrict__ xmax) {
  __shared__ int lc[N_SEG], ly0[N_SEG], ly1[N_SEG], lx0[N_SEG], lx1[N_SEG];
  int tid = threadIdx.x;
  if (tid < N_SEG) {
    lc[tid] = 0;
    ly0[tid] = 0x7fffffff; ly1[tid] = (int)0x80000000;
    lx0[tid] = 0x7fffffff; lx1[tid] = (int)0x80000000;
  }
  __syncthreads();
  int i = blockIdx.x * 256 + tid;
  int b = indices[i * 3], y = indices[i * 3 + 1], x = indices[i * 3 + 2];
  int s = seg[i];
  idx_map[(b * H_DIM + y) * W_DIM + x] = i;
  atomicAdd(&lc[s], 1);
  atomicMin(&ly0[s], y); atomicMax(&ly1[s], y);
  atomicMin(&lx0[s], x); atomicMax(&lx1[s], x);
  __syncthreads();
  if (tid < N_SEG && lc[tid] > 0) {
    atomicAdd(&cnt[tid], lc[tid]);
    atomicMin(&ymin[tid], ly0[tid]); atomicMax(&ymax[tid], ly1[tid]);
    atomicMin(&xmin[tid], lx0[tid]); atomicMax(&xmax[tid], lx1[tid]);
  }
}

__global__ void dilation_kernel(const int* ymin, const int* ymax,
                                const int* xmin, const int* xmax,
                                const int* cnt, int* dseg) {
  int t = threadIdx.x;
  if (t < 48) {
    int r = t >> 4, s = t & 15;
    int rate = (r == 0) ? 1 : (r == 1) ? 3 : 5;
    int d = 1;
    if (cnt[s] > 0) {
      float hr = (float)(ymax[s] - ymin[s]) * (1.0f / H_DIM);
      float wr = (float)(xmax[s] - xmin[s]) * (1.0f / W_DIM);
      d = (int)ceilf(fmaxf(hr, wr) * (float)rate);
      if (d < 1) d = 1;
    }
    dseg[t] = d;
  }
}

__global__ void convert_kernel(const float4* __restrict__ in, uint2* __restrict__ out, int n4) {
  int i = blockIdx.x * 256 + threadIdx.x;
  if (i < n4) {
    float4 v = in[i];
    union { bf16_t h[4]; uint2 u; } o;
    o.h[0] = (bf16_t)v.x; o.h[1] = (bf16_t)v.y;
    o.h[2] = (bf16_t)v.z; o.h[3] = (bf16_t)v.w;
    out[i] = o.u;
  }
}

// wfrag[s][k][kk][cot][lane][j]  s: 0..2 = w1..w3 ; 3..6 = wf row-slices p=0..3
__global__ void repack_kernel(const float* __restrict__ w1, const float* __restrict__ w2,
                              const float* __restrict__ w3, const float* __restrict__ wf,
                              bf16_t* __restrict__ wfrag) {
  int e = blockIdx.x * 256 + threadIdx.x;     // < 258048
  int s   = e / 36864;
  int rem = e % 36864;
  int k   = rem >> 12;
  int r2  = rem & 4095;
  int kk  = r2 >> 11;
  int r3  = r2 & 2047;
  int cot = r3 >> 9;
  int r4  = r3 & 511;
  int lane = r4 >> 3;
  int j    = r4 & 7;
  int c  = kk * 32 + (lane >> 4) * 8 + j;     // K index within 64-slice
  int co = cot * 16 + (lane & 15);            // output channel
  float v;
  if (s < 3) {
    const float* w = (s == 0) ? w1 : (s == 1) ? w2 : w3;
    v = w[k * 4096 + c * 64 + co];
  } else {
    int p = s - 3;
    v = wf[k * 16384 + (p * 64 + c) * 64 + co];
  }
  wfrag[e] = (bf16_t)v;
}

// MODE 0: branch conv (same-seg mask, per-seg dilation) -> write bf16 h
// MODE 1: final conv pass 0 (features)                  -> out = acc + bias
// MODE 2: final conv pass r (branch h)                  -> out += acc
template <int MODE>
__launch_bounds__(256)
__global__ void conv_mfma(const bf16_t* __restrict__ A,
                          const bf16_t* __restrict__ wfrag,
                          const int* __restrict__ indices,
                          const int* __restrict__ seg,
                          const int* __restrict__ idx_map,
                          const int* __restrict__ dseg,
                          float* __restrict__ outf,
                          bf16_t* __restrict__ outh,
                          const float* __restrict__ bias) {
  __shared__ int s_nbr[9 * 64];
  const int tid = threadIdx.x;
  const int pt0 = blockIdx.x * 64;

  for (int e = tid; e < 576; e += 256) {
    int k = e >> 6, row = e & 63;
    int pt = pt0 + row;
    int b = indices[pt * 3], y = indices[pt * 3 + 1], x = indices[pt * 3 + 2];
    int d = 1, sg = 0;
    if (MODE == 0) { sg = seg[pt]; d = dseg[sg]; }
    int ky = (k / 3) - 1, kx = (k % 3) - 1;
    int ny = y + ky * d, nx = x + kx * d;
    int nbr = -1;
    if (ny >= 0 && ny < H_DIM && nx >= 0 && nx < W_DIM) {
      nbr = idx_map[(b * H_DIM + ny) * W_DIM + nx];
      if (MODE == 0 && nbr >= 0 && seg[nbr] != sg) nbr = -1;
    }
    s_nbr[e] = nbr;
  }
  __syncthreads();

  const int lane = tid & 63;
  const int wv = tid >> 6;
  const int m = lane & 15;
  const int quad = lane >> 4;

  f32x4 acc[4];
#pragma unroll
  for (int c = 0; c < 4; ++c) { acc[c][0] = 0.f; acc[c][1] = 0.f; acc[c][2] = 0.f; acc[c][3] = 0.f; }

  const int rowm = wv * 16 + m;
  for (int k = 0; k < 9; ++k) {
    int nbr = s_nbr[k * 64 + rowm];
    const bf16_t* arow = A + (long)((nbr < 0) ? 0 : nbr) * 64 + quad * 8;
#pragma unroll
    for (int kk = 0; kk < 2; ++kk) {
      bf16x8 af;
      if (nbr >= 0) {
        af = *(const bf16x8*)(arow + kk * 32);
      } else {
#pragma unroll
        for (int j = 0; j < 8; ++j) af[j] = (bf16_t)0.0f;
      }
      const bf16_t* wb = wfrag + ((k * 2 + kk) * 4) * 512 + lane * 8;
#pragma unroll
      for (int cot = 0; cot < 4; ++cot) {
        bf16x8 bfv = *(const bf16x8*)(wb + cot * 512);
        acc[cot] = __builtin_amdgcn_mfma_f32_16x16x32_bf16(af, bfv, acc[cot], 0, 0, 0);
      }
    }
  }

#pragma unroll
  for (int reg = 0; reg < 4; ++reg) {
    int pt = pt0 + wv * 16 + quad * 4 + reg;
#pragma unroll
    for (int cot = 0; cot < 4; ++cot) {
      int col = cot * 16 + m;
      float v = acc[cot][reg];
      if (MODE == 0)      outh[(long)pt * 64 + col] = (bf16_t)v;
      else if (MODE == 1) outf[(long)pt * 64 + col] = v + bias[col];
      else                outf[(long)pt * 64 + col] += v;
    }
  }
}

__global__ void stats_kernel(const bf16_t* __restrict__ h,
                             const int* __restrict__ seg,
                             float* __restrict__ sums, float* __restrict__ sumsq) {
  int tid = threadIdx.x;
  int co = tid & 63, pr = tid >> 6;
  int base = blockIdx.x * 1024;
  float s = 0.f, s2 = 0.f;
  int cur = seg[base];
  for (int i = pr; i < 1024; i += 4) {
    int pt = base + i;
    int sg = seg[pt];
    float v = (float)h[(long)pt * 64 + co];
    if (sg != cur) {
      atomicAdd(&sums[cur * 64 + co], s);
      atomicAdd(&sumsq[cur * 64 + co], s2);
      s = 0.f; s2 = 0.f; cur = sg;
    }
    s += v; s2 += v * v;
  }
  atomicAdd(&sums[cur * 64 + co], s);
  atomicAdd(&sumsq[cur * 64 + co], s2);
}

__global__ void params_kernel(const int* __restrict__ cnt, const float* __restrict__ sums,
                              const float* __restrict__ sumsq,
                              float* __restrict__ pA, float* __restrict__ pB) {
  int t = blockIdx.x * 256 + threadIdx.x;
  if (t < 1024) {
    int sgi = t >> 6;
    float c = (float)cnt[sgi];
    float a = 0.f, b = 0.f;
    if (c > 0.f) {
      float mean = sums[t] / c;
      float var = sumsq[t] / c - mean * mean;
      float inv = rsqrtf(var + EPS_V);
      a = inv; b = -mean * inv;
    }
    pA[t] = a; pB[t] = b;
  }
}

__global__ void norm_kernel(bf16_t* __restrict__ h, const int* __restrict__ seg,
                            const float* __restrict__ pA, const float* __restrict__ pB) {
  int i = blockIdx.x * 256 + threadIdx.x;   // N*16 groups of 4 channels
  int pt = i >> 4;
  int cg = (i & 15) * 4;
  int sg = seg[pt];
  union { bf16_t hh[4]; uint2 u; } v;
  v.u = *(uint2*)(h + (long)pt * 64 + cg);
#pragma unroll
  for (int j = 0; j < 4; ++j) {
    float f = (float)v.hh[j] * pA[sg * 64 + cg + j] + pB[sg * 64 + cg + j];
    v.hh[j] = (bf16_t)fmaxf(f, 0.f);
  }
  *(uint2*)(h + (long)pt * 64 + cg) = v.u;
}

extern "C" void kernel_launch(void* const* d_in, const int* in_sizes, int n_in,
                              void* d_out, int out_size, void* d_ws, size_t ws_size,
                              hipStream_t stream) {
  const float* feats   = (const float*)d_in[0];
  const int*   indices = (const int*)d_in[1];
  const int*   seg     = (const int*)d_in[2];
  const float* w1 = (const float*)d_in[3];
  const float* w2 = (const float*)d_in[5];
  const float* w3 = (const float*)d_in[7];
  const float* wf = (const float*)d_in[9];
  const float* bf_ = (const float*)d_in[10];
  float* out = (float*)d_out;

  char* ws = (char*)d_ws;
  int*    idx_map  = (int*)(ws + 0);
  bf16_t* feats_bf = (bf16_t*)(ws + 4194304);
  bf16_t* h_bf     = (bf16_t*)(ws + 37748736);
  bf16_t* wfrag    = (bf16_t*)(ws + 71303168);
  float*  stats    = (float*)(ws + 71819264);
  int* cnt  = (int*)stats;
  int* ymin = (int*)(stats + 16);
  int* ymax = (int*)(stats + 32);
  int* xmin = (int*)(stats + 48);
  int* xmax = (int*)(stats + 64);
  int* dseg = (int*)(stats + 80);
  float* sums  = stats + 128;
  float* sumsq = stats + 3200;
  float* pA    = stats + 6272;
  float* pB    = stats + 9344;

  hipMemsetAsync(idx_map, 0xFF, 4194304, stream);
  init_kernel<<<1, 256, 0, stream>>>(cnt, ymin, ymax, xmin, xmax, sums, sumsq);
  scatter_kernel<<<N_PTS / 256, 256, 0, stream>>>(indices, seg, idx_map, cnt, ymin, ymax, xmin, xmax);
  dilation_kernel<<<1, 64, 0, stream>>>(ymin, ymax, xmin, xmax, cnt, dseg);
  convert_kernel<<<16384, 256, 0, stream>>>((const float4*)feats, (uint2*)feats_bf, N_PTS * 64 / 4);
  repack_kernel<<<1008, 256, 0, stream>>>(w1, w2, w3, wf, wfrag);

  // final conv, features slice (initializes out with bias)
  conv_mfma<1><<<4096, 256, 0, stream>>>(feats_bf, wfrag + (size_t)3 * 36864, indices, seg,
                                         idx_map, nullptr, out, nullptr, bf_);
  for (int r = 0; r < 3; ++r) {
    conv_mfma<0><<<4096, 256, 0, stream>>>(feats_bf, wfrag + (size_t)r * 36864, indices, seg,
                                           idx_map, dseg + r * 16, nullptr, h_bf, nullptr);
    stats_kernel<<<256, 256, 0, stream>>>(h_bf, seg, sums + r * 1024, sumsq + r * 1024);
    params_kernel<<<4, 256, 0, stream>>>(cnt, sums + r * 1024, sumsq + r * 1024,
                                         pA + r * 1024, pB + r * 1024);
    norm_kernel<<<16384, 256, 0, stream>>>(h_bf, seg, pA + r * 1024, pB + r * 1024);
    conv_mfma<2><<<4096, 256, 0, stream>>>(h_bf, wfrag + (size_t)(4 + r) * 36864, indices, seg,
                                           idx_map, nullptr, out, nullptr, nullptr);
  }
}

// Round 2
// 836.901 us; speedup vs baseline: 1.0670x; 1.0670x over previous
//
#include <hip/hip_runtime.h>
#include <hip/hip_bf16.h>
#include <stdint.h>

#define N_PTS   262144
#define H_DIM   512
#define W_DIM   512
#define N_SEG   16
#define EPS_V   1e-5f

typedef __bf16 bf16_t;
typedef __bf16 bf16x8 __attribute__((ext_vector_type(8)));
typedef float  f32x4  __attribute__((ext_vector_type(4)));

// ------------- workspace layouts -------------
// FUSED (ws >= ~139 MB):
//   idx_map int[4*512*512]            @ 0            (4194304)
//   cat     bf16[(N+1)*256]           @ 4194304      (134218240)   [feat|h1|h2|h3], row N = zeros
//   wfrag   bf16[258048]              @ 138412544    (516096)
//   stats   float/int                 @ 138928640    (~16 KB)
// FALLBACK:
//   idx_map                            @ 0
//   feats_bf bf16[(N+1)*64]           @ 4194304      (33554560)
//   h_bf     bf16[(N+1)*64]           @ 37748864     (33554560)
//   wfrag                              @ 71303424    (516096)
//   stats                              @ 71819520
// stats block (floats): cnt[16]@0 ymin@16 ymax@32 xmin@48 xmax@64 dseg[48]@80
//   sums[3*1024]@128 sumsq[3*1024]@3200 pA[3*1024]@6272 pB[3*1024]@9344

__global__ void init_kernel(int* cnt, int* ymin, int* ymax, int* xmin, int* xmax,
                            float* sums, float* sumsq) {
  int t = threadIdx.x;
  if (t < N_SEG) {
    cnt[t] = 0;
    ymin[t] = 0x7fffffff; ymax[t] = (int)0x80000000;
    xmin[t] = 0x7fffffff; xmax[t] = (int)0x80000000;
  }
  for (int i = t; i < 3 * 1024; i += 256) { sums[i] = 0.f; sumsq[i] = 0.f; }
}

__global__ void scatter_kernel(const int* __restrict__ indices,
                               const int* __restrict__ seg,
                               int* __restrict__ idx_map,
                               int* __restrict__ cnt,
                               int* __restrict__ ymin, int* __restrict__ ymax,
                               int* __restrict__ xmin, int* __restrict__ xmax) {
  __shared__ int lc[N_SEG], ly0[N_SEG], ly1[N_SEG], lx0[N_SEG], lx1[N_SEG];
  int tid = threadIdx.x;
  if (tid < N_SEG) {
    lc[tid] = 0;
    ly0[tid] = 0x7fffffff; ly1[tid] = (int)0x80000000;
    lx0[tid] = 0x7fffffff; lx1[tid] = (int)0x80000000;
  }
  __syncthreads();
  int i = blockIdx.x * 256 + tid;
  int b = indices[i * 3], y = indices[i * 3 + 1], x = indices[i * 3 + 2];
  int s = seg[i];
  idx_map[(b * H_DIM + y) * W_DIM + x] = i;
  atomicAdd(&lc[s], 1);
  atomicMin(&ly0[s], y); atomicMax(&ly1[s], y);
  atomicMin(&lx0[s], x); atomicMax(&lx1[s], x);
  __syncthreads();
  if (tid < N_SEG && lc[tid] > 0) {
    atomicAdd(&cnt[tid], lc[tid]);
    atomicMin(&ymin[tid], ly0[tid]); atomicMax(&ymax[tid], ly1[tid]);
    atomicMin(&xmin[tid], lx0[tid]); atomicMax(&xmax[tid], lx1[tid]);
  }
}

__global__ void dilation_kernel(const int* ymin, const int* ymax,
                                const int* xmin, const int* xmax,
                                const int* cnt, int* dseg) {
  int t = threadIdx.x;
  if (t < 48) {
    int r = t >> 4, s = t & 15;
    int rate = (r == 0) ? 1 : (r == 1) ? 3 : 5;
    int d = 1;
    if (cnt[s] > 0) {
      float hr = (float)(ymax[s] - ymin[s]) * (1.0f / H_DIM);
      float wr = (float)(xmax[s] - xmin[s]) * (1.0f / W_DIM);
      d = (int)ceilf(fmaxf(hr, wr) * (float)rate);
      if (d < 1) d = 1;
    }
    dseg[t] = d;
  }
}

// features fp32 -> bf16 rows of a strided buffer
__global__ void convert_kernel(const float4* __restrict__ in, bf16_t* __restrict__ dst,
                               int stride) {
  int i = blockIdx.x * 256 + threadIdx.x;   // N*16
  int pt = i >> 4, g = i & 15;
  float4 v = in[i];
  union { bf16_t h[4]; uint2 u; } o;
  o.h[0] = (bf16_t)v.x; o.h[1] = (bf16_t)v.y;
  o.h[2] = (bf16_t)v.z; o.h[3] = (bf16_t)v.w;
  *(uint2*)(dst + (size_t)pt * stride + g * 4) = o.u;
}

// wfrag: [0,110592): branch r in {0,1,2} at r*36864, layout [k][kk2][cot][lane][j]
//        [110592,258048): fused final, layout [k][kk8][cot][lane][j], kk8=0..7
__global__ void repack_kernel(const float* __restrict__ w1, const float* __restrict__ w2,
                              const float* __restrict__ w3, const float* __restrict__ wf,
                              bf16_t* __restrict__ wfrag) {
  int e = blockIdx.x * 256 + threadIdx.x;   // < 258048
  if (e < 110592) {
    int s = e / 36864, rem = e % 36864;
    int k = rem >> 12, r2 = rem & 4095;
    int kk = r2 >> 11, r3 = r2 & 2047;
    int cot = r3 >> 9, r4 = r3 & 511;
    int lane = r4 >> 3, j = r4 & 7;
    int c  = kk * 32 + (lane >> 4) * 8 + j;
    int co = cot * 16 + (lane & 15);
    const float* w = (s == 0) ? w1 : (s == 1) ? w2 : w3;
    wfrag[e] = (bf16_t)w[k * 4096 + c * 64 + co];
  } else {
    int ef = e - 110592;
    int k = ef >> 14, r2 = ef & 16383;
    int kk8 = r2 >> 11, r3 = r2 & 2047;
    int cot = r3 >> 9, r4 = r3 & 511;
    int lane = r4 >> 3, j = r4 & 7;
    int c  = kk8 * 32 + (lane >> 4) * 8 + j;   // 0..255
    int co = cot * 16 + (lane & 15);
    wfrag[e] = (bf16_t)wf[k * 16384 + c * 64 + co];
  }
}

// KK: number of 32-ch K-slices per neighbor (2 = 64ch, 8 = 256ch)
// MODE 0: branch conv (same-seg mask + dilation) -> bf16 outh slice
// MODE 1: final conv, out = acc + bias
// MODE 2: final conv accumulate pass (fallback), out += acc
template <int KK, int MODE>
__launch_bounds__(256)
__global__ void conv_mfma(const bf16_t* __restrict__ A, int astride,
                          const bf16_t* __restrict__ wfrag, int wkstride,
                          const int* __restrict__ indices,
                          const int* __restrict__ seg,
                          const int* __restrict__ idx_map,
                          const int* __restrict__ dseg,
                          float* __restrict__ outf,
                          bf16_t* __restrict__ outh, int hstride, int hoff,
                          const float* __restrict__ bias) {
  __shared__ int s_nbr[9 * 64];
  const int tid = threadIdx.x;
  const int pt0 = blockIdx.x * 64;

  for (int e = tid; e < 576; e += 256) {
    int k = e >> 6, row = e & 63;
    int pt = pt0 + row;
    int b = indices[pt * 3], y = indices[pt * 3 + 1], x = indices[pt * 3 + 2];
    int d = 1, sg = 0;
    if (MODE == 0) { sg = seg[pt]; d = dseg[sg]; }
    int ky = (k / 3) - 1, kx = (k % 3) - 1;
    int ny = y + ky * d, nx = x + kx * d;
    int nbr = N_PTS;                           // sentinel zero row
    if (ny >= 0 && ny < H_DIM && nx >= 0 && nx < W_DIM) {
      int t2 = idx_map[(b * H_DIM + ny) * W_DIM + nx];
      if (t2 >= 0) {
        if (MODE == 0) nbr = (seg[t2] == sg) ? t2 : N_PTS;
        else           nbr = t2;
      }
    }
    s_nbr[e] = nbr;
  }
  __syncthreads();

  const int lane = tid & 63;
  const int wv = tid >> 6;
  const int m = lane & 15;
  const int quad = lane >> 4;
  const int rowm = wv * 16 + m;

  f32x4 acc[4];
#pragma unroll
  for (int c = 0; c < 4; ++c) { acc[c][0] = 0.f; acc[c][1] = 0.f; acc[c][2] = 0.f; acc[c][3] = 0.f; }

  if constexpr (KK == 2) {
    // batch ALL 18 A-fragment gathers before the MFMA chain (max MLP)
    bf16x8 a[9][2];
#pragma unroll
    for (int k = 0; k < 9; ++k) {
      const bf16_t* ar = A + (size_t)s_nbr[k * 64 + rowm] * astride + quad * 8;
      a[k][0] = *(const bf16x8*)(ar);
      a[k][1] = *(const bf16x8*)(ar + 32);
    }
#pragma unroll
    for (int k = 0; k < 9; ++k) {
#pragma unroll
      for (int kk = 0; kk < 2; ++kk) {
        const bf16_t* wb = wfrag + k * wkstride + kk * 2048 + lane * 8;
#pragma unroll
        for (int cot = 0; cot < 4; ++cot)
          acc[cot] = __builtin_amdgcn_mfma_f32_16x16x32_bf16(
              a[k][kk], *(const bf16x8*)(wb + cot * 512), acc[cot], 0, 0, 0);
      }
    }
  } else {
    // KK == 8: double-buffer A over neighbors (8 loads in flight)
    bf16x8 a[2][8];
    {
      const bf16_t* ar = A + (size_t)s_nbr[rowm] * astride + quad * 8;
#pragma unroll
      for (int kk = 0; kk < 8; ++kk) a[0][kk] = *(const bf16x8*)(ar + kk * 32);
    }
#pragma unroll
    for (int k = 0; k < 9; ++k) {
      const int cur = k & 1, nxt = cur ^ 1;
      if (k < 8) {
        const bf16_t* ar = A + (size_t)s_nbr[(k + 1) * 64 + rowm] * astride + quad * 8;
#pragma unroll
        for (int kk = 0; kk < 8; ++kk) a[nxt][kk] = *(const bf16x8*)(ar + kk * 32);
      }
#pragma unroll
      for (int kk = 0; kk < 8; ++kk) {
        const bf16_t* wb = wfrag + k * wkstride + kk * 2048 + lane * 8;
#pragma unroll
        for (int cot = 0; cot < 4; ++cot)
          acc[cot] = __builtin_amdgcn_mfma_f32_16x16x32_bf16(
              a[cur][kk], *(const bf16x8*)(wb + cot * 512), acc[cot], 0, 0, 0);
      }
    }
  }

#pragma unroll
  for (int reg = 0; reg < 4; ++reg) {
    int pt = pt0 + wv * 16 + quad * 4 + reg;
#pragma unroll
    for (int cot = 0; cot < 4; ++cot) {
      int col = cot * 16 + m;
      float v = acc[cot][reg];
      if (MODE == 0)      outh[(size_t)pt * hstride + hoff + col] = (bf16_t)v;
      else if (MODE == 1) outf[(size_t)pt * 64 + col] = v + bias[col];
      else                outf[(size_t)pt * 64 + col] += v;
    }
  }
}

__global__ void stats_kernel(const bf16_t* __restrict__ h, int stride, int off,
                             const int* __restrict__ seg,
                             float* __restrict__ sums, float* __restrict__ sumsq) {
  int tid = threadIdx.x;
  int co = tid & 63, pr = tid >> 6;
  int base = blockIdx.x * 1024;
  float s = 0.f, s2 = 0.f;
  int cur = seg[base];
  for (int i = pr; i < 1024; i += 4) {
    int pt = base + i;
    int sg = seg[pt];
    float v = (float)h[(size_t)pt * stride + off + co];
    if (sg != cur) {
      atomicAdd(&sums[cur * 64 + co], s);
      atomicAdd(&sumsq[cur * 64 + co], s2);
      s = 0.f; s2 = 0.f; cur = sg;
    }
    s += v; s2 += v * v;
  }
  atomicAdd(&sums[cur * 64 + co], s);
  atomicAdd(&sumsq[cur * 64 + co], s2);
}

__global__ void params_kernel(const int* __restrict__ cnt, const float* __restrict__ sums,
                              const float* __restrict__ sumsq,
                              float* __restrict__ pA, float* __restrict__ pB) {
  int t = blockIdx.x * 256 + threadIdx.x;
  if (t < 1024) {
    int sgi = t >> 6;
    float c = (float)cnt[sgi];
    float a = 0.f, b = 0.f;
    if (c > 0.f) {
      float mean = sums[t] / c;
      float var = sumsq[t] / c - mean * mean;
      float inv = rsqrtf(var + EPS_V);
      a = inv; b = -mean * inv;
    }
    pA[t] = a; pB[t] = b;
  }
}

__global__ void norm_kernel(bf16_t* __restrict__ h, int stride, int off,
                            const int* __restrict__ seg,
                            const float* __restrict__ pA, const float* __restrict__ pB) {
  int i = blockIdx.x * 256 + threadIdx.x;   // N*16
  int pt = i >> 4;
  int cg = (i & 15) * 4;
  int sg = seg[pt];
  bf16_t* p = h + (size_t)pt * stride + off + cg;
  union { bf16_t hh[4]; uint2 u; } v;
  v.u = *(uint2*)p;
#pragma unroll
  for (int j = 0; j < 4; ++j) {
    float f = (float)v.hh[j] * pA[sg * 64 + cg + j] + pB[sg * 64 + cg + j];
    v.hh[j] = (bf16_t)fmaxf(f, 0.f);
  }
  *(uint2*)p = v.u;
}

extern "C" void kernel_launch(void* const* d_in, const int* in_sizes, int n_in,
                              void* d_out, int out_size, void* d_ws, size_t ws_size,
                              hipStream_t stream) {
  const float* feats   = (const float*)d_in[0];
  const int*   indices = (const int*)d_in[1];
  const int*   seg     = (const int*)d_in[2];
  const float* w1 = (const float*)d_in[3];
  const float* w2 = (const float*)d_in[5];
  const float* w3 = (const float*)d_in[7];
  const float* wf = (const float*)d_in[9];
  const float* bf_ = (const float*)d_in[10];
  float* out = (float*)d_out;

  char* ws = (char*)d_ws;
  const bool fused = (ws_size >= 139000000ull);

  int* idx_map = (int*)(ws + 0);
  hipMemsetAsync(idx_map, 0xFF, 4194304, stream);

  if (fused) {
    bf16_t* cat   = (bf16_t*)(ws + 4194304);           // (N+1) x 256
    bf16_t* wfrag = (bf16_t*)(ws + 138412544);
    float*  stats = (float*)(ws + 138928640);
    int* cnt  = (int*)stats;
    int* ymin = (int*)(stats + 16);
    int* ymax = (int*)(stats + 32);
    int* xmin = (int*)(stats + 48);
    int* xmax = (int*)(stats + 64);
    int* dseg = (int*)(stats + 80);
    float* sums  = stats + 128;
    float* sumsq = stats + 3200;
    float* pA    = stats + 6272;
    float* pB    = stats + 9344;

    hipMemsetAsync(cat + (size_t)N_PTS * 256, 0, 512, stream);   // sentinel row
    init_kernel<<<1, 256, 0, stream>>>(cnt, ymin, ymax, xmin, xmax, sums, sumsq);
    scatter_kernel<<<N_PTS / 256, 256, 0, stream>>>(indices, seg, idx_map, cnt, ymin, ymax, xmin, xmax);
    dilation_kernel<<<1, 64, 0, stream>>>(ymin, ymax, xmin, xmax, cnt, dseg);
    convert_kernel<<<16384, 256, 0, stream>>>((const float4*)feats, cat, 256);
    repack_kernel<<<1008, 256, 0, stream>>>(w1, w2, w3, wf, wfrag);

    for (int r = 0; r < 3; ++r) {
      conv_mfma<2, 0><<<4096, 256, 0, stream>>>(cat, 256, wfrag + (size_t)r * 36864, 4096,
                                                indices, seg, idx_map, dseg + r * 16,
                                                nullptr, cat, 256, (r + 1) * 64, nullptr);
      stats_kernel<<<256, 256, 0, stream>>>(cat, 256, (r + 1) * 64, seg,
                                            sums + r * 1024, sumsq + r * 1024);
      params_kernel<<<4, 256, 0, stream>>>(cnt, sums + r * 1024, sumsq + r * 1024,
                                           pA + r * 1024, pB + r * 1024);
      norm_kernel<<<16384, 256, 0, stream>>>(cat, 256, (r + 1) * 64, seg,
                                             pA + r * 1024, pB + r * 1024);
    }
    // fused final conv: K = 256 in one pass
    conv_mfma<8, 1><<<4096, 256, 0, stream>>>(cat, 256, wfrag + 110592, 16384,
                                              indices, seg, idx_map, nullptr,
                                              out, nullptr, 0, 0, bf_);
  } else {
    bf16_t* feats_bf = (bf16_t*)(ws + 4194304);        // (N+1) x 64
    bf16_t* h_bf     = (bf16_t*)(ws + 37748864);       // (N+1) x 64
    bf16_t* wfrag    = (bf16_t*)(ws + 71303424);
    float*  stats    = (float*)(ws + 71819520);
    int* cnt  = (int*)stats;
    int* ymin = (int*)(stats + 16);
    int* ymax = (int*)(stats + 32);
    int* xmin = (int*)(stats + 48);
    int* xmax = (int*)(stats + 64);
    int* dseg = (int*)(stats + 80);
    float* sums  = stats + 128;
    float* sumsq = stats + 3200;
    float* pA    = stats + 6272;
    float* pB    = stats + 9344;

    hipMemsetAsync(feats_bf + (size_t)N_PTS * 64, 0, 128, stream);
    hipMemsetAsync(h_bf + (size_t)N_PTS * 64, 0, 128, stream);
    init_kernel<<<1, 256, 0, stream>>>(cnt, ymin, ymax, xmin, xmax, sums, sumsq);
    scatter_kernel<<<N_PTS / 256, 256, 0, stream>>>(indices, seg, idx_map, cnt, ymin, ymax, xmin, xmax);
    dilation_kernel<<<1, 64, 0, stream>>>(ymin, ymax, xmin, xmax, cnt, dseg);
    convert_kernel<<<16384, 256, 0, stream>>>((const float4*)feats, feats_bf, 64);
    repack_kernel<<<1008, 256, 0, stream>>>(w1, w2, w3, wf, wfrag);

    // final conv pass 0: features slice (init with bias), uses fused-wfrag slice p=0
    conv_mfma<2, 1><<<4096, 256, 0, stream>>>(feats_bf, 64, wfrag + 110592, 16384,
                                              indices, seg, idx_map, nullptr,
                                              out, nullptr, 0, 0, bf_);
    for (int r = 0; r < 3; ++r) {
      conv_mfma<2, 0><<<4096, 256, 0, stream>>>(feats_bf, 64, wfrag + (size_t)r * 36864, 4096,
                                                indices, seg, idx_map, dseg + r * 16,
                                                nullptr, h_bf, 64, 0, nullptr);
      stats_kernel<<<256, 256, 0, stream>>>(h_bf, 64, 0, seg, sums + r * 1024, sumsq + r * 1024);
      params_kernel<<<4, 256, 0, stream>>>(cnt, sums + r * 1024, sumsq + r * 1024,
                                           pA + r * 1024, pB + r * 1024);
      norm_kernel<<<16384, 256, 0, stream>>>(h_bf, 64, 0, seg, pA + r * 1024, pB + r * 1024);
      conv_mfma<2, 2><<<4096, 256, 0, stream>>>(h_bf, 64, wfrag + 110592 + (size_t)(r + 1) * 4096, 16384,
                                                indices, seg, idx_map, nullptr,
                                                out, nullptr, 0, 0, nullptr);
    }
  }
}